// Round 4
// baseline (644.824 us; speedup 1.0000x reference)
//
#include <hip/hip_runtime.h>

#define NROWS 4096
#define HID 64

// ---------------- kernel 1: x=in@emb_w+b; q=x@q_w+b; kT=(x@k_w+b)^T; o pack
__global__ __launch_bounds__(64) void k_embed(
    const float* __restrict__ inp, const float* __restrict__ emb_w,
    const float* __restrict__ emb_b, const float* __restrict__ q_w,
    const float* __restrict__ q_b, const float* __restrict__ k_w,
    const float* __restrict__ k_b, float* __restrict__ q,
    float* __restrict__ kT, float* __restrict__ opk) {
  int row = blockIdx.x;
  int t = threadIdx.x;  // 64 threads
  __shared__ float in_s[8];
  __shared__ float x_s[64];
  if (t < 8) in_s[t] = inp[row * 8 + t];
  __syncthreads();
  float acc = emb_b[t];
#pragma unroll
  for (int i = 0; i < 8; ++i) acc += in_s[i] * emb_w[i * 64 + t];
  x_s[t] = acc;
  __syncthreads();
  float qa = q_b[t], ka = k_b[t];
#pragma unroll
  for (int i = 0; i < 64; ++i) {
    float xv = x_s[i];
    qa += xv * q_w[i * 64 + t];
    ka += xv * k_w[i * 64 + t];
  }
  q[row * 64 + t] = qa;
  kT[(size_t)t * NROWS + row] = ka;  // transposed store (tiny, one-off)
  if (t < 4) opk[row * 4 + t] = inp[row * 8 + 4 + t];
}

// ---------------- kernel 2: scores + single-pass in-register softmax ------
// 512 blocks x 512 thr (8 waves). Wave w owns row r0+w entirely: its 4096
// scores live in sv[16] float4 (64 floats/lane). Per 256-col tile the block
// stages kT[64][256] to LDS once; all 8 waves consume. Attn written ONCE.
__global__ __launch_bounds__(512, 2) void k_scores(
    const float* __restrict__ q, const float* __restrict__ kT,
    float* __restrict__ S, float* __restrict__ rowmax, float* __restrict__ rowsum) {
  __shared__ float4 kls[64][64];  // 64 KB: kT tile [c][col4]
  int t = threadIdx.x;
  int w = t >> 6;
  int g = t & 63;
  int row = blockIdx.x * 8 + w;
  float qa[64];
  const float4* qp = (const float4*)(q + (size_t)row * 64);
#pragma unroll
  for (int i = 0; i < 16; ++i) {
    float4 v = qp[i];
    qa[4 * i] = v.x * 0.125f;      // fold 1/sqrt(64) into q
    qa[4 * i + 1] = v.y * 0.125f;
    qa[4 * i + 2] = v.z * 0.125f;
    qa[4 * i + 3] = v.w * 0.125f;
  }
  float4 sv[16];
#pragma unroll
  for (int tile = 0; tile < 16; ++tile) {
    __syncthreads();
#pragma unroll
    for (int it = 0; it < 8; ++it) {
      int n = it * 512 + t;
      int c = n >> 6, c4 = n & 63;
      kls[c][c4] = *(const float4*)(kT + (size_t)c * NROWS + tile * 256 + c4 * 4);
    }
    __syncthreads();
    float a0 = 0.f, a1 = 0.f, a2 = 0.f, a3 = 0.f;
#pragma unroll
    for (int c = 0; c < 64; ++c) {
      float4 kv = kls[c][g];
      a0 += qa[c] * kv.x; a1 += qa[c] * kv.y;
      a2 += qa[c] * kv.z; a3 += qa[c] * kv.w;
    }
    sv[tile] = make_float4(a0, a1, a2, a3);
  }
  // in-register softmax over the wave's row
  float m = -1e30f;
#pragma unroll
  for (int tile = 0; tile < 16; ++tile) {
    float4 v = sv[tile];
    m = fmaxf(m, fmaxf(fmaxf(v.x, v.y), fmaxf(v.z, v.w)));
  }
#pragma unroll
  for (int off = 32; off > 0; off >>= 1) m = fmaxf(m, __shfl_xor(m, off, 64));
  float s = 0.f;
#pragma unroll
  for (int tile = 0; tile < 16; ++tile) {
    float4 v = sv[tile];
    v.x = __expf(v.x - m); v.y = __expf(v.y - m);
    v.z = __expf(v.z - m); v.w = __expf(v.w - m);
    sv[tile] = v;
    s += v.x + v.y + v.z + v.w;
  }
#pragma unroll
  for (int off = 32; off > 0; off >>= 1) s += __shfl_xor(s, off, 64);
  float li = 1.0f / s;
  float4* Sp = (float4*)(S + (size_t)row * NROWS);
#pragma unroll
  for (int tile = 0; tile < 16; ++tile) {
    float4 v = sv[tile];
    v.x *= li; v.y *= li; v.z *= li; v.w *= li;
    Sp[tile * 64 + g] = v;
  }
  if (g == 0) {
    rowmax[row] = m;
    rowsum[row] = s;
  }
}

// ---------------- kernel 3: ALL 10 conv layers fused (halo-10 LDS tile) ---
// 64x64 output tile; stage 84x84 input (zero-padded) into LDS; 10 stencil
// layers ping-pong in LDS, valid margin shrinks by 1 per layer; out-of-matrix
// positions forced to 0 every layer (zero-padding semantics).
#define TS 64
#define HALO 10
#define CW 84   // TS + 2*HALO
#define CWS 85  // padded LDS stride

__global__ __launch_bounds__(256) void k_conv_fused(
    const float* __restrict__ in, float* __restrict__ out,
    const float* __restrict__ w1p, const float* __restrict__ w2p,
    const float* __restrict__ ap) {
  __shared__ float buf[2][CW * CWS];
  int tid = threadIdx.x;
  int gi0 = blockIdx.y * TS - HALO;
  int gj0 = blockIdx.x * TS - HALO;
  // stage 84x84 (coalesced rows, zero-fill OOB)
  for (int idx = tid; idx < CW * CW; idx += 256) {
    int i = idx / CW, j = idx - i * CW;
    int gi = gi0 + i, gj = gj0 + j;
    float v = 0.f;
    if (gi >= 0 && gi < NROWS && gj >= 0 && gj < NROWS)
      v = in[(size_t)gi * NROWS + gj];
    buf[0][i * CWS + j] = v;
  }
  // column strips: thread owns column j, band of 28 rows; rolls vm/vc/vp
  int j = tid % CW;
  int band = tid / CW;  // 0..2 active, band 3 (tid>=252) idle
  int gj = gj0 + j;
  bool jin = (gj >= 0) && (gj < NROWS);
  for (int l = 0; l < 10; ++l) {
    float w10 = w1p[l * 3], w11 = w1p[l * 3 + 1], w12 = w1p[l * 3 + 2];
    float w20 = w2p[l * 3], w21 = w2p[l * 3 + 1], w22 = w2p[l * 3 + 2];
    float al = ap[l];
    float wc = w11 + w21;  // both center taps
    const float* src = buf[l & 1];
    float* dst = buf[(l + 1) & 1];
    __syncthreads();
    int m = l + 1;
    if (band < 3 && j >= m && j < CW - m) {
      int ilo = band * 28; if (ilo < m) ilo = m;
      int ihi = band * 28 + 28; if (ihi > CW - m) ihi = CW - m;
      if (ilo < ihi) {
        float vm = src[(ilo - 1) * CWS + j];
        float vc = src[ilo * CWS + j];
        for (int i = ilo; i < ihi; ++i) {
          float vp = src[(i + 1) * CWS + j];
          float lf = src[i * CWS + j - 1];
          float rt = src[i * CWS + j + 1];
          float o = w10 * lf + wc * vc + w12 * rt + w20 * vm + w22 * vp;
          o = (o >= 0.f) ? o : al * o;
          int gi = gi0 + i;
          bool ok = jin && (gi >= 0) && (gi < NROWS);
          dst[i * CWS + j] = ok ? o : 0.f;
          vm = vc; vc = vp;
        }
      }
    }
    __syncthreads();
  }
  // write inner 64x64 (final result in buf[0] after 10 layers)
  const float* fin = buf[0];
  for (int idx = tid; idx < TS * TS; idx += 256) {
    int i = idx >> 6, jj = idx & 63;
    out[(size_t)(gi0 + HALO + i) * NROWS + (gj0 + HALO + jj)] =
        fin[(HALO + i) * CWS + HALO + jj];
  }
}

// ---------------- kernel 5: calc = (conv>0)*softmax(s) @ o (recompute) ----
__global__ __launch_bounds__(256) void k_calc(
    const float* __restrict__ q, const float* __restrict__ kT,
    const float* __restrict__ conv, const float* __restrict__ opk,
    const float* __restrict__ rowmax, const float* __restrict__ rowsum,
    float* __restrict__ calc) {
  __shared__ float kls[64][256];  // 64 KB
  int t = threadIdx.x;
  int p = t >> 6;
  int g = t & 63;
  int r0 = blockIdx.x * 8;
  int rowA = r0 + p, rowB = rowA + 4;
  float qa[64], qb[64];
  const float4* qA = (const float4*)(q + (size_t)rowA * 64);
  const float4* qB = (const float4*)(q + (size_t)rowB * 64);
#pragma unroll
  for (int i = 0; i < 16; ++i) {
    float4 v = qA[i];
    qa[4 * i] = v.x; qa[4 * i + 1] = v.y; qa[4 * i + 2] = v.z; qa[4 * i + 3] = v.w;
    float4 w = qB[i];
    qb[4 * i] = w.x; qb[4 * i + 1] = w.y; qb[4 * i + 2] = w.z; qb[4 * i + 3] = w.w;
  }
  float mA = rowmax[rowA], liA = 1.0f / rowsum[rowA];
  float mB = rowmax[rowB], liB = 1.0f / rowsum[rowB];
  float acA0 = 0.f, acA1 = 0.f, acA2 = 0.f, acA3 = 0.f;
  float acB0 = 0.f, acB1 = 0.f, acB2 = 0.f, acB3 = 0.f;
  for (int tile = 0; tile < 16; ++tile) {
    __syncthreads();
#pragma unroll
    for (int it = 0; it < 16; ++it) {
      int c = it * 4 + p;
      float4 v = *(const float4*)(kT + (size_t)c * NROWS + tile * 256 + g * 4);
      *(float4*)(&kls[c][g * 4]) = v;
    }
    __syncthreads();
    float aA0 = 0.f, aA1 = 0.f, aA2 = 0.f, aA3 = 0.f;
    float aB0 = 0.f, aB1 = 0.f, aB2 = 0.f, aB3 = 0.f;
#pragma unroll
    for (int c = 0; c < 64; ++c) {
      float4 kv = *(float4*)(&kls[c][g * 4]);
      aA0 += qa[c] * kv.x; aA1 += qa[c] * kv.y; aA2 += qa[c] * kv.z; aA3 += qa[c] * kv.w;
      aB0 += qb[c] * kv.x; aB1 += qb[c] * kv.y; aB2 += qb[c] * kv.z; aB3 += qb[c] * kv.w;
    }
    int colb = tile * 256 + g * 4;
    float4 cA = *(const float4*)(conv + (size_t)rowA * NROWS + colb);
    float4 cB = *(const float4*)(conv + (size_t)rowB * NROWS + colb);
    const float4* op = (const float4*)opk + colb;
    float4 o0 = op[0], o1 = op[1], o2 = op[2], o3 = op[3];
    float wA0 = (cA.x > 0.f) ? __expf(aA0 * 0.125f - mA) * liA : 0.f;
    float wA1 = (cA.y > 0.f) ? __expf(aA1 * 0.125f - mA) * liA : 0.f;
    float wA2 = (cA.z > 0.f) ? __expf(aA2 * 0.125f - mA) * liA : 0.f;
    float wA3 = (cA.w > 0.f) ? __expf(aA3 * 0.125f - mA) * liA : 0.f;
    float wB0 = (cB.x > 0.f) ? __expf(aB0 * 0.125f - mB) * liB : 0.f;
    float wB1 = (cB.y > 0.f) ? __expf(aB1 * 0.125f - mB) * liB : 0.f;
    float wB2 = (cB.z > 0.f) ? __expf(aB2 * 0.125f - mB) * liB : 0.f;
    float wB3 = (cB.w > 0.f) ? __expf(aB3 * 0.125f - mB) * liB : 0.f;
    acA0 += wA0 * o0.x + wA1 * o1.x + wA2 * o2.x + wA3 * o3.x;
    acA1 += wA0 * o0.y + wA1 * o1.y + wA2 * o2.y + wA3 * o3.y;
    acA2 += wA0 * o0.z + wA1 * o1.z + wA2 * o2.z + wA3 * o3.z;
    acA3 += wA0 * o0.w + wA1 * o1.w + wA2 * o2.w + wA3 * o3.w;
    acB0 += wB0 * o0.x + wB1 * o1.x + wB2 * o2.x + wB3 * o3.x;
    acB1 += wB0 * o0.y + wB1 * o1.y + wB2 * o2.y + wB3 * o3.y;
    acB2 += wB0 * o0.z + wB1 * o1.z + wB2 * o2.z + wB3 * o3.z;
    acB3 += wB0 * o0.w + wB1 * o1.w + wB2 * o2.w + wB3 * o3.w;
  }
#pragma unroll
  for (int off = 32; off > 0; off >>= 1) {
    acA0 += __shfl_xor(acA0, off, 64); acA1 += __shfl_xor(acA1, off, 64);
    acA2 += __shfl_xor(acA2, off, 64); acA3 += __shfl_xor(acA3, off, 64);
    acB0 += __shfl_xor(acB0, off, 64); acB1 += __shfl_xor(acB1, off, 64);
    acB2 += __shfl_xor(acB2, off, 64); acB3 += __shfl_xor(acB3, off, 64);
  }
  if (g == 0) {
    calc[rowA * 4 + 0] = acA0; calc[rowA * 4 + 1] = acA1;
    calc[rowA * 4 + 2] = acA2; calc[rowA * 4 + 3] = acA3;
    calc[rowB * 4 + 0] = acB0; calc[rowB * 4 + 1] = acB1;
    calc[rowB * 4 + 2] = acB2; calc[rowB * 4 + 3] = acB3;
  }
}

// ---------------- kernel 6: gcn + mlp head --------------------------------
__global__ __launch_bounds__(64) void k_head(
    const float* __restrict__ calc, const float* __restrict__ gcn_w,
    const float* __restrict__ gcn_b, const float* __restrict__ gcn_a,
    const float* __restrict__ w1, const float* __restrict__ b1,
    const float* __restrict__ w2, const float* __restrict__ b2,
    float* __restrict__ out) {
  int row = blockIdx.x;
  int t = threadIdx.x;  // 64
  __shared__ float c4[4];
  __shared__ float gs[64];
  __shared__ float ms[32];
  if (t < 4) c4[t] = calc[row * 4 + t];
  __syncthreads();
  float g = gcn_b[t];
#pragma unroll
  for (int d = 0; d < 4; ++d) g += c4[d] * gcn_w[d * 64 + t];
  float ga = gcn_a[0];
  gs[t] = (g >= 0.f) ? g : ga * g;
  __syncthreads();
  if (t < 32) {
    float mm = b1[t];
#pragma unroll
    for (int i = 0; i < 64; ++i) mm += gs[i] * w1[i * 32 + t];
    ms[t] = fmaxf(mm, 0.f);
  }
  __syncthreads();
  if (t < 4) {
    float o = b2[t];
#pragma unroll
    for (int i = 0; i < 32; ++i) o += ms[i] * w2[i * 4 + t];
    out[row * 4 + t] = o;
  }
}

extern "C" void kernel_launch(void* const* d_in, const int* in_sizes, int n_in,
                              void* d_out, int out_size, void* d_ws, size_t ws_size,
                              hipStream_t stream) {
  (void)in_sizes; (void)n_in; (void)out_size; (void)ws_size;
  const float* inp    = (const float*)d_in[0];
  const float* emb_w  = (const float*)d_in[1];
  const float* emb_b  = (const float*)d_in[2];
  const float* q_w    = (const float*)d_in[3];
  const float* q_b    = (const float*)d_in[4];
  const float* k_w    = (const float*)d_in[5];
  const float* k_b    = (const float*)d_in[6];
  const float* conv_w1 = (const float*)d_in[7];
  const float* conv_w2 = (const float*)d_in[8];
  const float* conv_a  = (const float*)d_in[9];
  const float* gcn_w  = (const float*)d_in[10];
  const float* gcn_b  = (const float*)d_in[11];
  const float* gcn_a  = (const float*)d_in[12];
  const float* mlp_w1 = (const float*)d_in[13];
  const float* mlp_b1 = (const float*)d_in[14];
  const float* mlp_w2 = (const float*)d_in[15];
  const float* mlp_b2 = (const float*)d_in[16];
  float* out = (float*)d_out;

  const size_t NN = (size_t)NROWS * NROWS;
  float* A      = (float*)d_ws;              // 4096^2 attn
  float* B      = A + NN;                    // 4096^2 conv out
  float* q      = B + NN;                    // 4096*64
  float* kT     = q + (size_t)NROWS * HID;   // 64*4096 (transposed)
  float* opk    = kT + (size_t)NROWS * HID;  // 4096*4
  float* rowmax = opk + (size_t)NROWS * 4;
  float* rowsum = rowmax + NROWS;
  float* calc   = rowsum + NROWS;            // 4096*4

  k_embed<<<NROWS, 64, 0, stream>>>(inp, emb_w, emb_b, q_w, q_b, k_w, k_b, q, kT, opk);
  k_scores<<<NROWS / 8, 512, 0, stream>>>(q, kT, A, rowmax, rowsum);
  k_conv_fused<<<dim3(NROWS / TS, NROWS / TS), 256, 0, stream>>>(A, B, conv_w1,
                                                                 conv_w2, conv_a);
  k_calc<<<NROWS / 8, 256, 0, stream>>>(q, kT, B, opk, rowmax, rowsum, calc);
  k_head<<<NROWS, 64, 0, stream>>>(calc, gcn_w, gcn_b, gcn_a, mlp_w1, mlp_b1,
                                   mlp_w2, mlp_b2, out);
}

// Round 5
// 388.851 us; speedup vs baseline: 1.6583x; 1.6583x over previous
//
#include <hip/hip_runtime.h>

#define NROWS 4096
#define HID 64

// ---------------- kernel 1: x=in@emb_w+b; q=x@q_w+b; kT=(x@k_w+b)^T; o pack
__global__ __launch_bounds__(64) void k_embed(
    const float* __restrict__ inp, const float* __restrict__ emb_w,
    const float* __restrict__ emb_b, const float* __restrict__ q_w,
    const float* __restrict__ q_b, const float* __restrict__ k_w,
    const float* __restrict__ k_b, float* __restrict__ q,
    float* __restrict__ kT, float* __restrict__ opk) {
  int row = blockIdx.x;
  int t = threadIdx.x;  // 64 threads
  __shared__ float in_s[8];
  __shared__ float x_s[64];
  if (t < 8) in_s[t] = inp[row * 8 + t];
  __syncthreads();
  float acc = emb_b[t];
#pragma unroll
  for (int i = 0; i < 8; ++i) acc += in_s[i] * emb_w[i * 64 + t];
  x_s[t] = acc;
  __syncthreads();
  float qa = q_b[t], ka = k_b[t];
#pragma unroll
  for (int i = 0; i < 64; ++i) {
    float xv = x_s[i];
    qa += xv * q_w[i * 64 + t];
    ka += xv * k_w[i * 64 + t];
  }
  q[row * 64 + t] = qa;
  kT[(size_t)t * NROWS + row] = ka;  // transposed store (tiny, one-off)
  if (t < 4) opk[row * 4 + t] = inp[row * 8 + 4 + t];
}

// ---------------- kernel 2: scores + single-pass in-register softmax ------
__global__ __launch_bounds__(512, 2) void k_scores(
    const float* __restrict__ q, const float* __restrict__ kT,
    float* __restrict__ S, float* __restrict__ rowmax, float* __restrict__ rowsum) {
  __shared__ float4 kls[64][64];  // 64 KB: kT tile [c][col4]
  int t = threadIdx.x;
  int w = t >> 6;
  int g = t & 63;
  int row = blockIdx.x * 8 + w;
  float qa[64];
  const float4* qp = (const float4*)(q + (size_t)row * 64);
#pragma unroll
  for (int i = 0; i < 16; ++i) {
    float4 v = qp[i];
    qa[4 * i] = v.x * 0.125f;  // fold 1/sqrt(64) into q
    qa[4 * i + 1] = v.y * 0.125f;
    qa[4 * i + 2] = v.z * 0.125f;
    qa[4 * i + 3] = v.w * 0.125f;
  }
  float4 sv[16];
#pragma unroll
  for (int tile = 0; tile < 16; ++tile) {
    __syncthreads();
#pragma unroll
    for (int it = 0; it < 8; ++it) {
      int n = it * 512 + t;
      int c = n >> 6, c4 = n & 63;
      kls[c][c4] = *(const float4*)(kT + (size_t)c * NROWS + tile * 256 + c4 * 4);
    }
    __syncthreads();
    float a0 = 0.f, a1 = 0.f, a2 = 0.f, a3 = 0.f;
#pragma unroll
    for (int c = 0; c < 64; ++c) {
      float4 kv = kls[c][g];
      a0 += qa[c] * kv.x; a1 += qa[c] * kv.y;
      a2 += qa[c] * kv.z; a3 += qa[c] * kv.w;
    }
    sv[tile] = make_float4(a0, a1, a2, a3);
  }
  float m = -1e30f;
#pragma unroll
  for (int tile = 0; tile < 16; ++tile) {
    float4 v = sv[tile];
    m = fmaxf(m, fmaxf(fmaxf(v.x, v.y), fmaxf(v.z, v.w)));
  }
#pragma unroll
  for (int off = 32; off > 0; off >>= 1) m = fmaxf(m, __shfl_xor(m, off, 64));
  float s = 0.f;
#pragma unroll
  for (int tile = 0; tile < 16; ++tile) {
    float4 v = sv[tile];
    v.x = __expf(v.x - m); v.y = __expf(v.y - m);
    v.z = __expf(v.z - m); v.w = __expf(v.w - m);
    sv[tile] = v;
    s += v.x + v.y + v.z + v.w;
  }
#pragma unroll
  for (int off = 32; off > 0; off >>= 1) s += __shfl_xor(s, off, 64);
  float li = 1.0f / s;
  float4* Sp = (float4*)(S + (size_t)row * NROWS);
#pragma unroll
  for (int tile = 0; tile < 16; ++tile) {
    float4 v = sv[tile];
    v.x *= li; v.y *= li; v.z *= li; v.w *= li;
    Sp[tile * 64 + g] = v;
  }
  if (g == 0) {
    rowmax[row] = m;
    rowsum[row] = s;
  }
}

// ---------------- kernel 3: ALL 10 conv layers fused, float4 vectorized ---
// 64x64 output tile, stage 84x84 (zero-padded). Thread owns a float4 column
// group and a 4-row band; vertical register rolling; LDS reads are b128.
#define TS 64
#define HALO 10
#define CW 84
#define CWS 88  // dword stride: keeps row starts 16B-aligned

__global__ __launch_bounds__(512) void k_conv_fused(
    const float* __restrict__ in, float* __restrict__ out,
    const float* __restrict__ w1p, const float* __restrict__ w2p,
    const float* __restrict__ ap) {
  __shared__ float buf[2][CW * CWS];  // 2 x 28.9 KB
  int tid = threadIdx.x;
  int gi0 = blockIdx.y * TS - HALO;
  int gj0 = blockIdx.x * TS - HALO;
  // stage 84x84 (zero-fill outside matrix)
  for (int idx = tid; idx < CW * CW; idx += 512) {
    int i = idx / CW, j = idx - i * CW;
    int gi = gi0 + i, gj = gj0 + j;
    float v = 0.f;
    if (gi >= 0 && gi < NROWS && gj >= 0 && gj < NROWS)
      v = in[(size_t)gi * NROWS + gj];
    buf[0][i * CWS + j] = v;
  }
  int band = tid / 21;        // 21 bands of 4 rows cover 84 rows
  int j4 = tid - band * 21;   // 0..20 -> cols j4*4..j4*4+3
  int jb = j4 * 4;
  bool active = (band < 21);
  int r0b = band * 4;
  int jl = (jb - 1 < 0) ? 0 : jb - 1;
  int jr = (jb + 4 > CW - 1) ? CW - 1 : jb + 4;
  bool c0 = ((unsigned)(gj0 + jb + 0) < (unsigned)NROWS);
  bool c1 = ((unsigned)(gj0 + jb + 1) < (unsigned)NROWS);
  bool c2 = ((unsigned)(gj0 + jb + 2) < (unsigned)NROWS);
  bool c3 = ((unsigned)(gj0 + jb + 3) < (unsigned)NROWS);
  for (int l = 0; l < 10; ++l) {
    float w10 = w1p[3 * l], w12 = w1p[3 * l + 2];
    float w20 = w2p[3 * l], w22 = w2p[3 * l + 2];
    float wc = w1p[3 * l + 1] + w2p[3 * l + 1];
    float al = ap[l];
    const float* src = buf[l & 1];
    float* dst = buf[(l + 1) & 1];
    __syncthreads();
    int m = l + 1;
    if (active) {
      int rlo = (r0b < m) ? m : r0b;
      int rhi = (r0b + 4 < CW - m) ? r0b + 4 : CW - m;
      if (rlo < rhi) {
        float4 vm = *(const float4*)&src[(rlo - 1) * CWS + jb];
        float4 vc = *(const float4*)&src[rlo * CWS + jb];
        for (int r = rlo; r < rhi; ++r) {
          float4 vp = *(const float4*)&src[(r + 1) * CWS + jb];
          float lfs = src[r * CWS + jl];
          float rts = src[r * CWS + jr];
          float o0 = w10 * lfs + wc * vc.x + w12 * vc.y + w20 * vm.x + w22 * vp.x;
          float o1 = w10 * vc.x + wc * vc.y + w12 * vc.z + w20 * vm.y + w22 * vp.y;
          float o2 = w10 * vc.y + wc * vc.z + w12 * vc.w + w20 * vm.z + w22 * vp.z;
          float o3 = w10 * vc.z + wc * vc.w + w12 * rts + w20 * vm.w + w22 * vp.w;
          o0 = (o0 >= 0.f) ? o0 : al * o0;
          o1 = (o1 >= 0.f) ? o1 : al * o1;
          o2 = (o2 >= 0.f) ? o2 : al * o2;
          o3 = (o3 >= 0.f) ? o3 : al * o3;
          int grow = gi0 + r;
          bool rok = ((unsigned)grow < (unsigned)NROWS);
          float4 res;
          res.x = (rok && c0) ? o0 : 0.f;
          res.y = (rok && c1) ? o1 : 0.f;
          res.z = (rok && c2) ? o2 : 0.f;
          res.w = (rok && c3) ? o3 : 0.f;
          *(float4*)&dst[r * CWS + jb] = res;
          vm = vc; vc = vp;
        }
      }
    }
    __syncthreads();
  }
  // write inner 64x64 (result in buf[0] after 10 layers)
  const float* fin = buf[0];
  for (int idx = tid; idx < TS * TS / 4; idx += 512) {
    int i = idx >> 4;            // row 0..63 (16 float4 per row)
    int jj = (idx & 15) * 4;
    int base = (HALO + i) * CWS + HALO + jj;
    float4 v;
    v.x = fin[base + 0];
    v.y = fin[base + 1];
    v.z = fin[base + 2];
    v.w = fin[base + 3];
    *(float4*)&out[(size_t)(gi0 + HALO + i) * NROWS + (gj0 + HALO + jj)] = v;
  }
}

// ---------------- kernel 5: calc = (conv>0)*attn @ o (pure streaming) -----
// 512 blocks x 512 thr; wave w owns row blockIdx*8+w. attn kept in A.
__global__ __launch_bounds__(512) void k_calc(
    const float* __restrict__ attn, const float* __restrict__ conv,
    const float* __restrict__ opk, float* __restrict__ calc) {
  int t = threadIdx.x;
  int w = t >> 6;
  int g = t & 63;
  int row = blockIdx.x * 8 + w;
  const float4* Ap = (const float4*)(attn + (size_t)row * NROWS);
  const float4* Bp = (const float4*)(conv + (size_t)row * NROWS);
  float a0 = 0.f, a1 = 0.f, a2 = 0.f, a3 = 0.f;
#pragma unroll 4
  for (int it = 0; it < 16; ++it) {
    int j4 = it * 64 + g;
    float4 av = Ap[j4];
    float4 bv = Bp[j4];
    const float4* op = (const float4*)opk + (size_t)j4 * 4;
    float4 o0 = op[0], o1 = op[1], o2 = op[2], o3 = op[3];
    float wa0 = (bv.x > 0.f) ? av.x : 0.f;
    float wa1 = (bv.y > 0.f) ? av.y : 0.f;
    float wa2 = (bv.z > 0.f) ? av.z : 0.f;
    float wa3 = (bv.w > 0.f) ? av.w : 0.f;
    a0 += wa0 * o0.x + wa1 * o1.x + wa2 * o2.x + wa3 * o3.x;
    a1 += wa0 * o0.y + wa1 * o1.y + wa2 * o2.y + wa3 * o3.y;
    a2 += wa0 * o0.z + wa1 * o1.z + wa2 * o2.z + wa3 * o3.z;
    a3 += wa0 * o0.w + wa1 * o1.w + wa2 * o2.w + wa3 * o3.w;
  }
#pragma unroll
  for (int off = 32; off > 0; off >>= 1) {
    a0 += __shfl_xor(a0, off, 64);
    a1 += __shfl_xor(a1, off, 64);
    a2 += __shfl_xor(a2, off, 64);
    a3 += __shfl_xor(a3, off, 64);
  }
  if (g == 0) {
    float4 r = {a0, a1, a2, a3};
    *(float4*)&calc[row * 4] = r;
  }
}

// ---------------- kernel 6: gcn + mlp head --------------------------------
__global__ __launch_bounds__(64) void k_head(
    const float* __restrict__ calc, const float* __restrict__ gcn_w,
    const float* __restrict__ gcn_b, const float* __restrict__ gcn_a,
    const float* __restrict__ w1, const float* __restrict__ b1,
    const float* __restrict__ w2, const float* __restrict__ b2,
    float* __restrict__ out) {
  int row = blockIdx.x;
  int t = threadIdx.x;  // 64
  __shared__ float c4[4];
  __shared__ float gs[64];
  __shared__ float ms[32];
  if (t < 4) c4[t] = calc[row * 4 + t];
  __syncthreads();
  float g = gcn_b[t];
#pragma unroll
  for (int d = 0; d < 4; ++d) g += c4[d] * gcn_w[d * 64 + t];
  float ga = gcn_a[0];
  gs[t] = (g >= 0.f) ? g : ga * g;
  __syncthreads();
  if (t < 32) {
    float mm = b1[t];
#pragma unroll
    for (int i = 0; i < 64; ++i) mm += gs[i] * w1[i * 32 + t];
    ms[t] = fmaxf(mm, 0.f);
  }
  __syncthreads();
  if (t < 4) {
    float o = b2[t];
#pragma unroll
    for (int i = 0; i < 32; ++i) o += ms[i] * w2[i * 4 + t];
    out[row * 4 + t] = o;
  }
}

extern "C" void kernel_launch(void* const* d_in, const int* in_sizes, int n_in,
                              void* d_out, int out_size, void* d_ws, size_t ws_size,
                              hipStream_t stream) {
  (void)in_sizes; (void)n_in; (void)out_size; (void)ws_size;
  const float* inp    = (const float*)d_in[0];
  const float* emb_w  = (const float*)d_in[1];
  const float* emb_b  = (const float*)d_in[2];
  const float* q_w    = (const float*)d_in[3];
  const float* q_b    = (const float*)d_in[4];
  const float* k_w    = (const float*)d_in[5];
  const float* k_b    = (const float*)d_in[6];
  const float* conv_w1 = (const float*)d_in[7];
  const float* conv_w2 = (const float*)d_in[8];
  const float* conv_a  = (const float*)d_in[9];
  const float* gcn_w  = (const float*)d_in[10];
  const float* gcn_b  = (const float*)d_in[11];
  const float* gcn_a  = (const float*)d_in[12];
  const float* mlp_w1 = (const float*)d_in[13];
  const float* mlp_b1 = (const float*)d_in[14];
  const float* mlp_w2 = (const float*)d_in[15];
  const float* mlp_b2 = (const float*)d_in[16];
  float* out = (float*)d_out;

  const size_t NN = (size_t)NROWS * NROWS;
  float* A      = (float*)d_ws;              // 4096^2 attn (kept)
  float* B      = A + NN;                    // 4096^2 conv out
  float* q      = B + NN;                    // 4096*64
  float* kT     = q + (size_t)NROWS * HID;   // 64*4096 (transposed)
  float* opk    = kT + (size_t)NROWS * HID;  // 4096*4
  float* rowmax = opk + (size_t)NROWS * 4;
  float* rowsum = rowmax + NROWS;
  float* calc   = rowsum + NROWS;            // 4096*4

  k_embed<<<NROWS, 64, 0, stream>>>(inp, emb_w, emb_b, q_w, q_b, k_w, k_b, q, kT, opk);
  k_scores<<<NROWS / 8, 512, 0, stream>>>(q, kT, A, rowmax, rowsum);
  k_conv_fused<<<dim3(NROWS / TS, NROWS / TS), 512, 0, stream>>>(A, B, conv_w1,
                                                                 conv_w2, conv_a);
  k_calc<<<NROWS / 8, 512, 0, stream>>>(A, B, opk, calc);
  k_head<<<NROWS, 64, 0, stream>>>(calc, gcn_w, gcn_b, gcn_a, mlp_w1, mlp_b1,
                                   mlp_w2, mlp_b2, out);
}

// Round 6
// 276.637 us; speedup vs baseline: 2.3309x; 1.4056x over previous
//
#include <hip/hip_runtime.h>

#define NROWS 4096
#define HID 64

// ---------------- kernel 1: x=in@emb_w+b; q=x@q_w+b; kT=(x@k_w+b)^T; o pack
__global__ __launch_bounds__(64) void k_embed(
    const float* __restrict__ inp, const float* __restrict__ emb_w,
    const float* __restrict__ emb_b, const float* __restrict__ q_w,
    const float* __restrict__ q_b, const float* __restrict__ k_w,
    const float* __restrict__ k_b, float* __restrict__ q,
    float* __restrict__ kT, float* __restrict__ opk) {
  int row = blockIdx.x;
  int t = threadIdx.x;  // 64 threads
  __shared__ float in_s[8];
  __shared__ float x_s[64];
  if (t < 8) in_s[t] = inp[row * 8 + t];
  __syncthreads();
  float acc = emb_b[t];
#pragma unroll
  for (int i = 0; i < 8; ++i) acc += in_s[i] * emb_w[i * 64 + t];
  x_s[t] = acc;
  __syncthreads();
  float qa = q_b[t], ka = k_b[t];
#pragma unroll
  for (int i = 0; i < 64; ++i) {
    float xv = x_s[i];
    qa += xv * q_w[i * 64 + t];
    ka += xv * k_w[i * 64 + t];
  }
  q[row * 64 + t] = qa;
  kT[(size_t)t * NROWS + row] = ka;
  if (t < 4) opk[row * 4 + t] = inp[row * 8 + 4 + t];
}

// ---------------- kernel 2: scores + single-pass in-register softmax ------
__global__ __launch_bounds__(512, 2) void k_scores(
    const float* __restrict__ q, const float* __restrict__ kT,
    float* __restrict__ S) {
  __shared__ float4 kls[64][64];  // 64 KB: kT tile [c][col4]
  int t = threadIdx.x;
  int w = t >> 6;
  int g = t & 63;
  int row = blockIdx.x * 8 + w;
  float qa[64];
  const float4* qp = (const float4*)(q + (size_t)row * 64);
#pragma unroll
  for (int i = 0; i < 16; ++i) {
    float4 v = qp[i];
    qa[4 * i] = v.x * 0.125f;  // fold 1/sqrt(64) into q
    qa[4 * i + 1] = v.y * 0.125f;
    qa[4 * i + 2] = v.z * 0.125f;
    qa[4 * i + 3] = v.w * 0.125f;
  }
  float4 sv[16];
#pragma unroll
  for (int tile = 0; tile < 16; ++tile) {
    __syncthreads();
#pragma unroll
    for (int it = 0; it < 8; ++it) {
      int n = it * 512 + t;
      int c = n >> 6, c4 = n & 63;
      kls[c][c4] = *(const float4*)(kT + (size_t)c * NROWS + tile * 256 + c4 * 4);
    }
    __syncthreads();
    float a0 = 0.f, a1 = 0.f, a2 = 0.f, a3 = 0.f;
#pragma unroll
    for (int c = 0; c < 64; ++c) {
      float4 kv = kls[c][g];
      a0 += qa[c] * kv.x; a1 += qa[c] * kv.y;
      a2 += qa[c] * kv.z; a3 += qa[c] * kv.w;
    }
    sv[tile] = make_float4(a0, a1, a2, a3);
  }
  float m = -1e30f;
#pragma unroll
  for (int tile = 0; tile < 16; ++tile) {
    float4 v = sv[tile];
    m = fmaxf(m, fmaxf(fmaxf(v.x, v.y), fmaxf(v.z, v.w)));
  }
#pragma unroll
  for (int off = 32; off > 0; off >>= 1) m = fmaxf(m, __shfl_xor(m, off, 64));
  float s = 0.f;
#pragma unroll
  for (int tile = 0; tile < 16; ++tile) {
    float4 v = sv[tile];
    v.x = __expf(v.x - m); v.y = __expf(v.y - m);
    v.z = __expf(v.z - m); v.w = __expf(v.w - m);
    sv[tile] = v;
    s += v.x + v.y + v.z + v.w;
  }
#pragma unroll
  for (int off = 32; off > 0; off >>= 1) s += __shfl_xor(s, off, 64);
  float li = 1.0f / s;
  float4* Sp = (float4*)(S + (size_t)row * NROWS);
#pragma unroll
  for (int tile = 0; tile < 16; ++tile) {
    float4 v = sv[tile];
    v.x *= li; v.y *= li; v.z *= li; v.w *= li;
    Sp[tile * 64 + g] = v;
  }
}

// ---------------- kernel 3: 10 fused conv layers + masked-dot epilogue ----
// 64x64 output tile; staged 84x84 in LDS (CWS=84, 16B aligned rows).
// Wave = 3 bands x 21 lanes (lane 63 idle); band owns 4 rows x 4 cols group.
// Left/right neighbors via __shfl (no conflicted scalar LDS reads).
// Epilogue: partial[tj][row][4] = sum_j (conv>0)*attn*o — conv never hits HBM.
#define TS 64
#define HALO 10
#define CW 84
#define CWS 84

__global__ __launch_bounds__(512) void k_conv_fused(
    const float* __restrict__ attn, float* __restrict__ partial,
    const float* __restrict__ w1p, const float* __restrict__ w2p,
    const float* __restrict__ ap, const float* __restrict__ opk) {
  __shared__ float buf[2][CW * CWS];  // 2 x 27.6 KB
  int tid = threadIdx.x;
  int gi0 = blockIdx.y * TS - HALO;
  int gj0 = blockIdx.x * TS - HALO;
  bool edge = (blockIdx.x == 0) || (blockIdx.x == gridDim.x - 1) ||
              (blockIdx.y == 0) || (blockIdx.y == gridDim.y - 1);
  // stage 84x84
  if (edge) {
    for (int idx = tid; idx < CW * CW; idx += 512) {
      int i = idx / CW, j = idx - i * CW;
      int gi = gi0 + i, gj = gj0 + j;
      float v = 0.f;
      if ((unsigned)gi < (unsigned)NROWS && (unsigned)gj < (unsigned)NROWS)
        v = attn[(size_t)gi * NROWS + gj];
      buf[0][idx] = v;
    }
  } else {
    for (int idx = tid; idx < CW * CW; idx += 512) {
      int i = idx / CW, j = idx - i * CW;
      buf[0][idx] = attn[(size_t)(gi0 + i) * NROWS + (gj0 + j)];
    }
  }
  // band mapping: 3 bands per wave, 21 lanes each (lane 63 idle)
  int wv = tid >> 6, lane = tid & 63;
  int sub = lane / 21;            // 0..2 (3 -> idle)
  int j4 = lane - sub * 21;       // 0..20
  int band = wv * 3 + sub;        // 0..23; active bands 0..20
  bool active = (sub < 3) && (band < 21);
  int jb = j4 * 4;
  int r0b = band * 4;
  bool c0 = false, c1 = false, c2 = false, c3 = false;
  if (edge) {
    c0 = ((unsigned)(gj0 + jb + 0) < (unsigned)NROWS);
    c1 = ((unsigned)(gj0 + jb + 1) < (unsigned)NROWS);
    c2 = ((unsigned)(gj0 + jb + 2) < (unsigned)NROWS);
    c3 = ((unsigned)(gj0 + jb + 3) < (unsigned)NROWS);
  }
  for (int l = 0; l < 10; ++l) {
    float w10 = w1p[3 * l], w12 = w1p[3 * l + 2];
    float w20 = w2p[3 * l], w22 = w2p[3 * l + 2];
    float wc = w1p[3 * l + 1] + w2p[3 * l + 1];
    float al = ap[l];
    const float* src = buf[l & 1];
    float* dst = buf[(l + 1) & 1];
    __syncthreads();
    int m = l + 1;
    if (active) {
      int rlo = (r0b < m) ? m : r0b;
      int rhi = (r0b + 4 < CW - m) ? r0b + 4 : CW - m;
      if (rlo < rhi) {
        float4 vm = *(const float4*)&src[(rlo - 1) * CWS + jb];
        float4 vc = *(const float4*)&src[rlo * CWS + jb];
        for (int r = rlo; r < rhi; ++r) {
          float4 vp = *(const float4*)&src[(r + 1) * CWS + jb];
          float lup = __shfl_up(vc.w, 1, 64);
          float rdn = __shfl_down(vc.x, 1, 64);
          float lfs = (j4 == 0) ? vc.x : lup;
          float rts = (j4 == 20) ? vc.w : rdn;
          float o0 = w10 * lfs + wc * vc.x + w12 * vc.y + w20 * vm.x + w22 * vp.x;
          float o1 = w10 * vc.x + wc * vc.y + w12 * vc.z + w20 * vm.y + w22 * vp.y;
          float o2 = w10 * vc.y + wc * vc.z + w12 * vc.w + w20 * vm.z + w22 * vp.z;
          float o3 = w10 * vc.z + wc * vc.w + w12 * rts + w20 * vm.w + w22 * vp.w;
          o0 = (o0 >= 0.f) ? o0 : al * o0;
          o1 = (o1 >= 0.f) ? o1 : al * o1;
          o2 = (o2 >= 0.f) ? o2 : al * o2;
          o3 = (o3 >= 0.f) ? o3 : al * o3;
          float4 res = {o0, o1, o2, o3};
          if (edge) {
            bool rok = ((unsigned)(gi0 + r) < (unsigned)NROWS);
            res.x = (rok && c0) ? o0 : 0.f;
            res.y = (rok && c1) ? o1 : 0.f;
            res.z = (rok && c2) ? o2 : 0.f;
            res.w = (rok && c3) ? o3 : 0.f;
          }
          *(float4*)&dst[r * CWS + jb] = res;
          vm = vc; vc = vp;
        }
      }
    } else {
      // keep shuffles well-defined (sources are in-band only, but be safe)
    }
    __syncthreads();
  }
  // epilogue: masked dot over the inner 64x64; result tile is in buf[0]
  const float* fin = buf[0];
  int i = tid >> 3;        // 0..63 row in tile
  int part = tid & 7;      // 8 lanes per row
  int gi = gi0 + HALO + i;
  float a0 = 0.f, a1 = 0.f, a2 = 0.f, a3 = 0.f;
#pragma unroll
  for (int k = 0; k < 8; ++k) {
    int jj = part * 8 + k;
    float cf = fin[(HALO + i) * CWS + HALO + jj];
    if (cf > 0.f) {
      int gj = gj0 + HALO + jj;
      float av = attn[(size_t)gi * NROWS + gj];
      const float4 ov = *(const float4*)(opk + (size_t)gj * 4);
      a0 += av * ov.x; a1 += av * ov.y; a2 += av * ov.z; a3 += av * ov.w;
    }
  }
#pragma unroll
  for (int off = 1; off < 8; off <<= 1) {
    a0 += __shfl_xor(a0, off, 64);
    a1 += __shfl_xor(a1, off, 64);
    a2 += __shfl_xor(a2, off, 64);
    a3 += __shfl_xor(a3, off, 64);
  }
  if (part == 0) {
    float4 r = {a0, a1, a2, a3};
    *(float4*)&partial[((size_t)blockIdx.x * NROWS + gi) * 4] = r;
  }
}

// ---------------- kernel 4: reduce partials + gcn + mlp head --------------
__global__ __launch_bounds__(64) void k_head(
    const float* __restrict__ partial, const float* __restrict__ gcn_w,
    const float* __restrict__ gcn_b, const float* __restrict__ gcn_a,
    const float* __restrict__ w1, const float* __restrict__ b1,
    const float* __restrict__ w2, const float* __restrict__ b2,
    float* __restrict__ out) {
  int row = blockIdx.x;
  int t = threadIdx.x;  // 64
  __shared__ float c4[4];
  __shared__ float gs[64];
  __shared__ float ms[32];
  // reduce 64 tile-partials: c = t&3, g = t>>2 sums tj = g+16u
  {
    int c = t & 3, gg = t >> 2;
    float s = 0.f;
#pragma unroll
    for (int u = 0; u < 4; ++u) {
      int tj = gg + 16 * u;
      s += partial[((size_t)tj * NROWS + row) * 4 + c];
    }
#pragma unroll
    for (int off = 4; off < 64; off <<= 1) s += __shfl_xor(s, off, 64);
    if (t < 4) c4[t] = s;
  }
  __syncthreads();
  float g = gcn_b[t];
#pragma unroll
  for (int d = 0; d < 4; ++d) g += c4[d] * gcn_w[d * 64 + t];
  float ga = gcn_a[0];
  gs[t] = (g >= 0.f) ? g : ga * g;
  __syncthreads();
  if (t < 32) {
    float mm = b1[t];
#pragma unroll
    for (int i = 0; i < 64; ++i) mm += gs[i] * w1[i * 32 + t];
    ms[t] = fmaxf(mm, 0.f);
  }
  __syncthreads();
  if (t < 4) {
    float o = b2[t];
#pragma unroll
    for (int i = 0; i < 32; ++i) o += ms[i] * w2[i * 4 + t];
    out[row * 4 + t] = o;
  }
}

extern "C" void kernel_launch(void* const* d_in, const int* in_sizes, int n_in,
                              void* d_out, int out_size, void* d_ws, size_t ws_size,
                              hipStream_t stream) {
  (void)in_sizes; (void)n_in; (void)out_size; (void)ws_size;
  const float* inp    = (const float*)d_in[0];
  const float* emb_w  = (const float*)d_in[1];
  const float* emb_b  = (const float*)d_in[2];
  const float* q_w    = (const float*)d_in[3];
  const float* q_b    = (const float*)d_in[4];
  const float* k_w    = (const float*)d_in[5];
  const float* k_b    = (const float*)d_in[6];
  const float* conv_w1 = (const float*)d_in[7];
  const float* conv_w2 = (const float*)d_in[8];
  const float* conv_a  = (const float*)d_in[9];
  const float* gcn_w  = (const float*)d_in[10];
  const float* gcn_b  = (const float*)d_in[11];
  const float* gcn_a  = (const float*)d_in[12];
  const float* mlp_w1 = (const float*)d_in[13];
  const float* mlp_b1 = (const float*)d_in[14];
  const float* mlp_w2 = (const float*)d_in[15];
  const float* mlp_b2 = (const float*)d_in[16];
  float* out = (float*)d_out;

  const size_t NN = (size_t)NROWS * NROWS;
  float* A       = (float*)d_ws;               // 4096^2 attn
  float* partial = A + NN;                     // 64 * 4096 * 4 = 4M floats
  float* q       = partial + (size_t)64 * NROWS * 4;
  float* kT      = q + (size_t)NROWS * HID;
  float* opk     = kT + (size_t)NROWS * HID;   // 4096*4

  k_embed<<<NROWS, 64, 0, stream>>>(inp, emb_w, emb_b, q_w, q_b, k_w, k_b, q, kT, opk);
  k_scores<<<NROWS / 8, 512, 0, stream>>>(q, kT, A);
  k_conv_fused<<<dim3(NROWS / TS, NROWS / TS), 512, 0, stream>>>(A, partial, conv_w1,
                                                                 conv_w2, conv_a, opk);
  k_head<<<NROWS, 64, 0, stream>>>(partial, gcn_w, gcn_b, gcn_a, mlp_w1, mlp_b1,
                                   mlp_w2, mlp_b2, out);
}